// Round 2
// 122.781 us; speedup vs baseline: 1.0215x; 1.0215x over previous
//
#include <hip/hip_runtime.h>

#define NEGV -1e30f

// Problem constants (fixed by setup_inputs)
constexpr int Bn = 8, Ci = 64, Hn = 64, Wn = 64, Co = 64;

// Mapping: lane = co (64 lanes = 64 output channels); each wave owns G=4
// consecutive output pixels of one row. The x window is wave-uniform ->
// readfirstlane forces the address chain into SGPRs so the 18 window loads
// per ci are s_load (values in SGPRs, zero VALU cost). Weights are the vector
// operand via transposed wT[ci][k][co]: 9 coalesced global_load_dword per ci,
// SGPR-advanced base + k*Co immediate offsets. Inner loop = pure core:
// 4 px * (9 v_add + 4 v_max3 + 1 v_max) = 56 VALU per ci.
// Grid (4,64,8) = 2048 blocks -> 8 blocks/CU, 32 waves/CU.
constexpr int G  = 4;        // pixels per wave
constexpr int CW = Wn / G;   // 16 chunks per row

// ---------- pre-pass: wT[ci][k][co] = wt[co][ci][k]  (147456 B in d_ws) ----
__global__ __launch_bounds__(256)
void wtrans_kernel(const float* __restrict__ wt, float* __restrict__ wT) {
    int idx = blockIdx.x * 256 + threadIdx.x;
    if (idx < Ci * 9 * Co) {
        int co = idx & 63;
        int k  = (idx >> 6) % 9;
        int ci = idx / (9 * Co);
        wT[idx] = wt[((size_t)co * Ci + ci) * 9 + k];
    }
}

// EDGE: 0 = interior, 1 = left chunk (w0==0), 2 = right chunk (w0==Wn-G).
// xv[c] corresponds to input column (cb+c); border columns are NEGV at
// compile time, so no per-lane masking ever happens.
template<int EDGE>
__device__ __forceinline__ void load6(float* xv, const float* __restrict__ p) {
    if (EDGE == 1) {
        xv[0] = NEGV;
#pragma unroll
        for (int c = 1; c < 6; c++) xv[c] = p[c - 1];   // cols 0..4
    } else if (EDGE == 2) {
#pragma unroll
        for (int c = 0; c < 5; c++) xv[c] = p[c];       // cols 59..63
        xv[5] = NEGV;
    } else {
#pragma unroll
        for (int c = 0; c < 6; c++) xv[c] = p[c];       // cols w0-1..w0+4
    }
}

template<int EDGE>
__device__ __forceinline__ void run_wave(const float* __restrict__ x,
                                         const float* __restrict__ wT,
                                         float* __restrict__ out,
                                         int b, int h, int w0, int lane) {
    const bool hasUp = (h > 0);        // wave-uniform (blockIdx-derived)
    const bool hasDn = (h < Hn - 1);
    const int  cb    = (EDGE == 1) ? 0 : (w0 - 1);   // first loaded column

    // wave-uniform x row pointer (center row h); w0/cb are readfirstlane'd in
    // the caller so this whole chain is SGPR arithmetic -> s_load window.
    const float* px = x + (((size_t)b * Ci) * Hn + h) * Wn + cb;
    // per-lane weight pointer: wT + lane; k*Co reachable via imm offsets
    const float* pw = wT + lane;

    float a[G];
#pragma unroll
    for (int p = 0; p < G; p++) a[p] = NEGV;

    for (int ci = 0; ci < Ci; ci++, px += Hn * Wn, pw += 9 * Co) {
        // scalar (SGPR) x window: rows h-1, h, h+1, cols cb..cb+5
        float xu[6], xc[6], xd[6];
        load6<EDGE>(xc, px);
        if (hasUp) load6<EDGE>(xu, px - Wn);
        else {
#pragma unroll
            for (int c = 0; c < 6; c++) xu[c] = NEGV;
        }
        if (hasDn) load6<EDGE>(xd, px + Wn);
        else {
#pragma unroll
            for (int c = 0; c < 6; c++) xd[c] = NEGV;
        }

        // vector weights: 9 coalesced dword loads, this lane's co
        float wv[9];
#pragma unroll
        for (int k = 0; k < 9; k++) wv[k] = pw[k * Co];

        // pure core: per pixel 9 v_add (sgpr+vgpr) + 4 v_max3 + 1 v_max
#pragma unroll
        for (int p = 0; p < G; p++) {
            float t0 = xu[p] + wv[0], t1 = xu[p + 1] + wv[1], t2 = xu[p + 2] + wv[2];
            float t3 = xc[p] + wv[3], t4 = xc[p + 1] + wv[4], t5 = xc[p + 2] + wv[5];
            float t6 = xd[p] + wv[6], t7 = xd[p + 1] + wv[7], t8 = xd[p + 2] + wv[8];
            float v = a[p];
            v = fmaxf(v, fmaxf(t0, t1));   // v_max3
            v = fmaxf(v, fmaxf(t2, t3));
            v = fmaxf(v, fmaxf(t4, t5));
            v = fmaxf(v, fmaxf(t6, t7));
            v = fmaxf(v, t8);
            a[p] = v;
        }
    }

    // lane holds 4 consecutive w for its co -> one dwordx4 store per lane
    float4 st = make_float4(a[0], a[1], a[2], a[3]);
    *reinterpret_cast<float4*>(out + (((size_t)b * Co + lane) * Hn + h) * Wn + w0) = st;
}

__global__ __launch_bounds__(256, 8)
void maxconv_main(const float* __restrict__ x, const float* __restrict__ wT,
                  float* __restrict__ out) {
    const int lane = threadIdx.x & 63;
    const int wid  = threadIdx.x >> 6;           // 0..3, wave-uniform in fact
    // readfirstlane makes cw PROVABLY uniform so the x-window address chain
    // selects to SGPR arithmetic + s_load (otherwise divergence analysis
    // treats threadIdx-derived wid as divergent -> vector loads).
    const int cw   = __builtin_amdgcn_readfirstlane(blockIdx.x * 4 + wid);
    const int w0   = cw * G;
    const int h    = blockIdx.y;
    const int b    = blockIdx.z;

    if (cw == 0)           run_wave<1>(x, wT, out, b, h, w0, lane);
    else if (cw == CW - 1) run_wave<2>(x, wT, out, b, h, w0, lane);
    else                   run_wave<0>(x, wT, out, b, h, w0, lane);
}

extern "C" void kernel_launch(void* const* d_in, const int* in_sizes, int n_in,
                              void* d_out, int out_size, void* d_ws, size_t ws_size,
                              hipStream_t stream) {
    const float* x  = (const float*)d_in[0];
    const float* wt = (const float*)d_in[1];
    float* out = (float*)d_out;
    float* wT  = (float*)d_ws;   // 64*9*64*4 = 147456 B, recomputed every launch

    wtrans_kernel<<<(Ci * 9 * Co + 255) / 256, 256, 0, stream>>>(wt, wT);

    dim3 grid(CW / 4, Hn, Bn);   // (4, 64, 8) = 2048 blocks = 8/CU = 32 waves/CU
    maxconv_main<<<grid, 256, 0, stream>>>(x, wT, out);
}

// Round 3
// 122.036 us; speedup vs baseline: 1.0277x; 1.0061x over previous
//
#include <hip/hip_runtime.h>

#define NEGV -1e30f

// Problem constants (fixed by setup_inputs)
constexpr int Bn = 8, Ci = 64, Hn = 64, Wn = 64, Co = 64;

// Mapping (verified round 2): lane = co; each wave owns G=4 consecutive output
// pixels of one row. x window is wave-uniform -> s_load into SGPRs; weights
// are the vector operand via transposed wT[ci][k][co] (9 coalesced dword
// loads/ci, prefetched one ci ahead, vmcnt in-order). Core forced to minimal
// VALU via inline-asm v_max3_f32: per px exactly 9 v_add + 4 v_max3 + 1 v_max.
constexpr int G  = 4;        // pixels per wave
constexpr int CW = Wn / G;   // 16 chunks per row

// ---------- pre-pass: wT[ci][k][co] = wt[co][ci][k]  (147456 B in d_ws) ----
__global__ __launch_bounds__(256)
void wtrans_kernel(const float* __restrict__ wt, float* __restrict__ wT) {
    int idx = blockIdx.x * 256 + threadIdx.x;
    if (idx < Ci * 9 * Co) {
        int co = idx & 63;
        int k  = (idx >> 6) % 9;
        int ci = idx / (9 * Co);
        wT[idx] = wt[((size_t)co * Ci + ci) * 9 + k];
    }
}

// Forced single-instruction 3-input max (no portable builtin; without
// fast-math the compiler often fails to form v_max3 from fmaxf chains).
__device__ __forceinline__ float vmax3(float a, float b, float c) {
    float d;
    asm("v_max3_f32 %0, %1, %2, %3" : "=v"(d) : "v"(a), "v"(b), "v"(c));
    return d;
}

// EDGE: 0 = interior, 1 = left chunk (w0==0), 2 = right chunk (w0==Wn-G).
// xv[c] corresponds to input column (cb+c); border columns are NEGV at
// compile time, so no per-lane masking ever happens.
template<int EDGE>
__device__ __forceinline__ void load6(float* xv, const float* __restrict__ p) {
    if (EDGE == 1) {
        xv[0] = NEGV;
#pragma unroll
        for (int c = 1; c < 6; c++) xv[c] = p[c - 1];   // cols 0..4
    } else if (EDGE == 2) {
#pragma unroll
        for (int c = 0; c < 5; c++) xv[c] = p[c];       // cols 59..63
        xv[5] = NEGV;
    } else {
#pragma unroll
        for (int c = 0; c < 6; c++) xv[c] = p[c];       // cols w0-1..w0+4
    }
}

struct Win { float u[6], c[6], d[6]; };

template<int EDGE>
__device__ __forceinline__ void loadwin(Win& w, const float* __restrict__ px,
                                        bool hasUp, bool hasDn) {
    load6<EDGE>(w.c, px);
    if (hasUp) load6<EDGE>(w.u, px - Wn);
    else {
#pragma unroll
        for (int c = 0; c < 6; c++) w.u[c] = NEGV;
    }
    if (hasDn) load6<EDGE>(w.d, px + Wn);
    else {
#pragma unroll
        for (int c = 0; c < 6; c++) w.d[c] = NEGV;
    }
}

__device__ __forceinline__ void loadw(float* wv, const float* __restrict__ wrow,
                                      int lane) {
#pragma unroll
    for (int k = 0; k < 9; k++) wv[k] = wrow[k * Co + lane];
}

__device__ __forceinline__ void compute(float* a, const Win& w, const float* wv) {
#pragma unroll
    for (int p = 0; p < G; p++) {
        float t0 = w.u[p] + wv[0], t1 = w.u[p + 1] + wv[1], t2 = w.u[p + 2] + wv[2];
        float t3 = w.c[p] + wv[3], t4 = w.c[p + 1] + wv[4], t5 = w.c[p + 2] + wv[5];
        float t6 = w.d[p] + wv[6], t7 = w.d[p + 1] + wv[7], t8 = w.d[p + 2] + wv[8];
        float m0 = vmax3(t0, t1, t2);
        float m1 = vmax3(t3, t4, t5);
        float m2 = vmax3(t6, t7, t8);
        a[p] = vmax3(a[p], m0, m1);
        a[p] = fmaxf(a[p], m2);
    }
}

template<int EDGE>
__device__ __forceinline__ void run_wave(const float* __restrict__ x,
                                         const float* __restrict__ wT,
                                         float* __restrict__ out,
                                         int b, int h, int w0, int lane) {
    const bool hasUp = (h > 0);        // wave-uniform (blockIdx-derived)
    const bool hasDn = (h < Hn - 1);
    const int  cb    = (EDGE == 1) ? 0 : (w0 - 1);   // first loaded column

    // wave-uniform x row pointer (center row h); SGPR chain -> s_load window
    const float* px   = x + (((size_t)b * Ci) * Hn + h) * Wn + cb;
    // uniform weight-row pointer; lane offset is the (constant) VGPR index
    const float* wrow = wT;

    float a[G];
#pragma unroll
    for (int p = 0; p < G; p++) a[p] = NEGV;

    // Ping-pong: weights prefetched one ci ahead (VMEM, in-order waits);
    // x window s_loads stay per-iteration (SMEM unordered: prefetching them
    // would force a full-drain wait on the just-issued batch).
    Win wA, wB;
    float vA[9], vB[9];

    loadw(vA, wrow, lane);  wrow += 9 * Co;   // weights ci=0

#pragma unroll 1
    for (int ci = 0; ci < Ci - 2; ci += 2) {
        loadw(vB, wrow, lane);  wrow += 9 * Co;         // weights ci+1
        loadwin<EDGE>(wA, px, hasUp, hasDn);  px += Hn * Wn;
        compute(a, wA, vA);                             // ci
        loadw(vA, wrow, lane);  wrow += 9 * Co;         // weights ci+2
        loadwin<EDGE>(wB, px, hasUp, hasDn);  px += Hn * Wn;
        compute(a, wB, vB);                             // ci+1
    }
    // ci = 62, 63 (no further weight prefetch)
    loadw(vB, wrow, lane);
    loadwin<EDGE>(wA, px, hasUp, hasDn);  px += Hn * Wn;
    compute(a, wA, vA);
    loadwin<EDGE>(wB, px, hasUp, hasDn);
    compute(a, wB, vB);

    // lane holds 4 consecutive w for its co -> one dwordx4 store per lane
    float4 st = make_float4(a[0], a[1], a[2], a[3]);
    *reinterpret_cast<float4*>(out + (((size_t)b * Co + lane) * Hn + h) * Wn + w0) = st;
}

__global__ __launch_bounds__(256, 8)
void maxconv_main(const float* __restrict__ x, const float* __restrict__ wT,
                  float* __restrict__ out) {
    const int lane = threadIdx.x & 63;
    const int wid  = threadIdx.x >> 6;           // 0..3, wave-uniform in fact
    // readfirstlane makes cw PROVABLY uniform so the x-window address chain
    // selects to SGPR arithmetic + s_load.
    const int cw   = __builtin_amdgcn_readfirstlane(blockIdx.x * 4 + wid);
    const int w0   = cw * G;
    const int h    = blockIdx.y;
    const int b    = blockIdx.z;

    if (cw == 0)           run_wave<1>(x, wT, out, b, h, w0, lane);
    else if (cw == CW - 1) run_wave<2>(x, wT, out, b, h, w0, lane);
    else                   run_wave<0>(x, wT, out, b, h, w0, lane);
}

extern "C" void kernel_launch(void* const* d_in, const int* in_sizes, int n_in,
                              void* d_out, int out_size, void* d_ws, size_t ws_size,
                              hipStream_t stream) {
    const float* x  = (const float*)d_in[0];
    const float* wt = (const float*)d_in[1];
    float* out = (float*)d_out;
    float* wT  = (float*)d_ws;   // 64*9*64*4 = 147456 B, recomputed every launch

    wtrans_kernel<<<(Ci * 9 * Co + 255) / 256, 256, 0, stream>>>(wt, wT);

    dim3 grid(CW / 4, Hn, Bn);   // (4, 64, 8) = 2048 blocks = 8/CU, 32 waves/CU
    maxconv_main<<<grid, 256, 0, stream>>>(x, wT, out);
}

// Round 4
// 120.435 us; speedup vs baseline: 1.0414x; 1.0133x over previous
//
#include <hip/hip_runtime.h>

#define NEGV -1e30f

// Problem constants (fixed by setup_inputs)
constexpr int Bn = 8, Ci = 64, Hn = 64, Wn = 64, Co = 64;

// Mapping: lane = co; wave owns G=8 consecutive output pixels of one row.
// x window is wave-uniform -> s_load into SGPRs, software-pipelined one ci
// ahead (wait -> issue-next -> compute-current; SMEM is unordered so the only
// wait is lgkmcnt(0), hence the rotation). Weights are the vector operand via
// wT[ci][k][co], ping-pong prefetched (vmcnt, in-order). Core: per px
// 9 v_add + 4 v_max3 + 1 v_max (forced). Grid: 1024 blocks, 1-D, swizzled so
// id%8 == h>>3: each XCD owns an 8-row h-band -> x L2-resident per XCD.
constexpr int G  = 8;        // pixels per wave
constexpr int CW = Wn / G;   // 8 chunks per row

// ---------- pre-pass: wT[ci][k][co] = wt[co][ci][k]  (147456 B in d_ws) ----
__global__ __launch_bounds__(256)
void wtrans_kernel(const float* __restrict__ wt, float* __restrict__ wT) {
    int idx = blockIdx.x * 256 + threadIdx.x;
    if (idx < Ci * 9 * Co) {
        int co = idx & 63;
        int k  = (idx >> 6) % 9;
        int ci = idx / (9 * Co);
        wT[idx] = wt[((size_t)co * Ci + ci) * 9 + k];
    }
}

__device__ __forceinline__ float vmax3(float a, float b, float c) {
    float d;
    asm("v_max3_f32 %0, %1, %2, %3" : "=v"(d) : "v"(a), "v"(b), "v"(c));
    return d;
}

// EDGE: 0 = interior, 1 = left chunk (w0==0), 2 = right chunk (w0==Wn-G).
// xv[c] = input column (cb+c); border columns are NEGV at compile time.
template<int EDGE>
__device__ __forceinline__ void load10(float* xv, const float* __restrict__ p) {
    if (EDGE == 1) {                       // cb = 0, cols 0..8
        xv[0] = NEGV;
#pragma unroll
        for (int c = 1; c < 10; c++) xv[c] = p[c - 1];
    } else if (EDGE == 2) {                // cb = 55, cols 55..63
#pragma unroll
        for (int c = 0; c < 9; c++) xv[c] = p[c];
        xv[9] = NEGV;
    } else {                               // cols w0-1 .. w0+8
#pragma unroll
        for (int c = 0; c < 10; c++) xv[c] = p[c];
    }
}

struct Win { float u[10], c[10], d[10]; };

template<int EDGE>
__device__ __forceinline__ void loadwin(Win& w, const float* __restrict__ px,
                                        bool hasUp, bool hasDn) {
    load10<EDGE>(w.c, px);
    if (hasUp) load10<EDGE>(w.u, px - Wn);
    else {
#pragma unroll
        for (int c = 0; c < 10; c++) w.u[c] = NEGV;
    }
    if (hasDn) load10<EDGE>(w.d, px + Wn);
    else {
#pragma unroll
        for (int c = 0; c < 10; c++) w.d[c] = NEGV;
    }
}

__device__ __forceinline__ void loadw(float* wv, const float* __restrict__ wrow,
                                      int lane) {
#pragma unroll
    for (int k = 0; k < 9; k++) wv[k] = wrow[k * Co + lane];  // imm offs k*256B
}

__device__ __forceinline__ void compute(float* a, const Win& w, const float* wv) {
#pragma unroll
    for (int p = 0; p < G; p++) {
        float t0 = w.u[p] + wv[0], t1 = w.u[p + 1] + wv[1], t2 = w.u[p + 2] + wv[2];
        float t3 = w.c[p] + wv[3], t4 = w.c[p + 1] + wv[4], t5 = w.c[p + 2] + wv[5];
        float t6 = w.d[p] + wv[6], t7 = w.d[p + 1] + wv[7], t8 = w.d[p + 2] + wv[8];
        float m0 = vmax3(t0, t1, t2);
        float m1 = vmax3(t3, t4, t5);
        float m2 = vmax3(t6, t7, t8);
        a[p] = vmax3(a[p], m0, m1);
        a[p] = fmaxf(a[p], m2);
    }
}

#define SMEM_DRAIN() do {                                   \
    asm volatile("s_waitcnt lgkmcnt(0)" ::: "memory");      \
    __builtin_amdgcn_sched_barrier(0);                      \
} while (0)

template<int EDGE>
__device__ __forceinline__ void run_wave(const float* __restrict__ x,
                                         const float* __restrict__ wT,
                                         float* __restrict__ out,
                                         int b, int h, int w0, int lane) {
    const bool hasUp = (h > 0);        // wave-uniform
    const bool hasDn = (h < Hn - 1);
    const int  cb    = (EDGE == 1) ? 0 : (w0 - 1);

    const float* px   = x + (((size_t)b * Ci) * Hn + h) * Wn + cb;
    const float* wrow = wT;

    float a[G];
#pragma unroll
    for (int p = 0; p < G; p++) a[p] = NEGV;

    Win wA, wB;
    float vA[9], vB[9];

    // prologue: ci=0 in flight
    loadw(vA, wrow, lane);  wrow += 9 * Co;
    loadwin<EDGE>(wA, px, hasUp, hasDn);  px += Hn * Wn;

#pragma unroll 1
    for (int ci = 0; ci < Ci - 2; ci += 2) {
        SMEM_DRAIN();                                        // wA ready
        loadwin<EDGE>(wB, px, hasUp, hasDn);  px += Hn * Wn; // issue ci+1
        __builtin_amdgcn_sched_barrier(0);
        loadw(vB, wrow, lane);  wrow += 9 * Co;              // weights ci+1
        compute(a, wA, vA);                                  // ci (covers wB latency)

        SMEM_DRAIN();                                        // wB ready
        loadwin<EDGE>(wA, px, hasUp, hasDn);  px += Hn * Wn; // issue ci+2
        __builtin_amdgcn_sched_barrier(0);
        loadw(vA, wrow, lane);  wrow += 9 * Co;              // weights ci+2
        compute(a, wB, vB);                                  // ci+1
    }
    // ci = 62, 63
    SMEM_DRAIN();
    loadwin<EDGE>(wB, px, hasUp, hasDn);
    __builtin_amdgcn_sched_barrier(0);
    loadw(vB, wrow, lane);
    compute(a, wA, vA);
    SMEM_DRAIN();
    compute(a, wB, vB);

    // lane holds 8 consecutive w for its co -> two dwordx4 stores
    float* po = out + (((size_t)b * Co + lane) * Hn + h) * Wn + w0;
    *reinterpret_cast<float4*>(po)     = make_float4(a[0], a[1], a[2], a[3]);
    *reinterpret_cast<float4*>(po + 4) = make_float4(a[4], a[5], a[6], a[7]);
}

__global__ __launch_bounds__(256, 4)
void maxconv_main(const float* __restrict__ x, const float* __restrict__ wT,
                  float* __restrict__ out) {
    const int lane = threadIdx.x & 63;
    const int wid  = threadIdx.x >> 6;           // 0..3

    // XCD h-band swizzle: id%8 == h>>3, so each XCD's L2 owns an 8-row band
    // (working set rows h-1..h+8 x 64ci x 8b ~= 1.3 MB, L2-resident).
    const int id   = blockIdx.x;                 // 0..1023
    const int band = id & 7;
    const int t    = id >> 3;
    const int bx   = t & 1;                      // chunk group
    const int u    = t >> 1;
    const int h    = band * 8 + (u & 7);
    const int b    = u >> 3;

    // readfirstlane: provably uniform -> x-window chain is SGPR + s_load
    const int cw   = __builtin_amdgcn_readfirstlane(bx * 4 + wid);  // 0..7
    const int w0   = cw * G;

    if (cw == 0)           run_wave<1>(x, wT, out, b, h, w0, lane);
    else if (cw == CW - 1) run_wave<2>(x, wT, out, b, h, w0, lane);
    else                   run_wave<0>(x, wT, out, b, h, w0, lane);
}

extern "C" void kernel_launch(void* const* d_in, const int* in_sizes, int n_in,
                              void* d_out, int out_size, void* d_ws, size_t ws_size,
                              hipStream_t stream) {
    const float* x  = (const float*)d_in[0];
    const float* wt = (const float*)d_in[1];
    float* out = (float*)d_out;
    float* wT  = (float*)d_ws;   // 64*9*64*4 = 147456 B

    wtrans_kernel<<<(Ci * 9 * Co + 255) / 256, 256, 0, stream>>>(wt, wT);

    // 1024 blocks = 4/CU, 16 waves/CU; 4 waves/SIMD x 224 cyc compute per ci
    // fully covers one pipelined SMEM batch latency.
    maxconv_main<<<1024, 256, 0, stream>>>(x, wT, out);
}